// Round 1
// baseline (269.372 us; speedup 1.0000x reference)
//
#include <hip/hip_runtime.h>
#include <cstdint>
#include <math.h>

typedef _Float16 f16;
typedef _Float16 f16x8 __attribute__((ext_vector_type(8)));
typedef float    f32x4 __attribute__((ext_vector_type(4)));

__device__ __forceinline__ f32x4 mfma16(f16x8 a, f16x8 b, f32x4 c) {
  return __builtin_amdgcn_mfma_f32_16x16x32_f16(a, b, c, 0, 0, 0);
}

// async global->LDS, 16B per lane; deposit = wave-uniform base + lane*16
__device__ __forceinline__ void gl2lds16(const f16* g, f16* l) {
  __builtin_amdgcn_global_load_lds((__attribute__((address_space(1))) void*)(g),
                                   (__attribute__((address_space(3))) void*)(l),
                                   16, 0, 0);
}

// ---------------- fp32 -> f16 conversion of x, Wq|Wk|Wv (stacked), Wo ----------------
__global__ __launch_bounds__(256) void cvt_kernel(
    const float* __restrict__ x,  const float* __restrict__ wq, const float* __restrict__ wk,
    const float* __restrict__ wv, const float* __restrict__ wo,
    f16* __restrict__ xh, f16* __restrict__ wqkvh, f16* __restrict__ woh)
{
  const int seg = blockIdx.y;
  const float* src; f16* dst; int n;
  if      (seg == 0) { src = x;  dst = xh;              n = 4194304; }
  else if (seg == 1) { src = wq; dst = wqkvh;           n = 1048576; }
  else if (seg == 2) { src = wk; dst = wqkvh + 1048576; n = 1048576; }
  else if (seg == 3) { src = wv; dst = wqkvh + 2097152; n = 1048576; }
  else               { src = wo; dst = woh;             n = 1048576; }
  const int idx = (int)(blockIdx.x * 256 + threadIdx.x) * 8;
  if (idx >= n) return;
  f32x4 a = *(const f32x4*)(src + idx);
  f32x4 b = *(const f32x4*)(src + idx + 4);
  f16x8 h;
  h[0] = (f16)a[0]; h[1] = (f16)a[1]; h[2] = (f16)a[2]; h[3] = (f16)a[3];
  h[4] = (f16)b[0]; h[5] = (f16)b[1]; h[6] = (f16)b[2]; h[7] = (f16)b[3];
  *(f16x8*)(dst + idx) = h;
}

// ---------------- NT GEMM, 128x128 tile, BK=32, m97-style staging ----------------
// MODE 0: A=[4096x1024]=x, B=[3072x1024]=Wq|Wk|Wv; scatter epilogue -> Q/K/V [B,H,S,64] f16 (+bias)
// MODE 1: A=[4096x1024]=ctx, B=[1024x1024]=Wo; epilogue -> out fp32 (+bias)
template<int MODE>
__global__ __launch_bounds__(256) void gemm_nt(
    const f16* __restrict__ A, const f16* __restrict__ B,
    const float* __restrict__ bias0, const float* __restrict__ bias1, const float* __restrict__ bias2,
    f16* __restrict__ Qp, f16* __restrict__ Kp, f16* __restrict__ Vp,
    float* __restrict__ OutF)
{
  constexpr int K = 1024;
  __shared__ __align__(16) f16 As[128 * 32];
  __shared__ __align__(16) f16 Bs[128 * 32];
  const int tid  = threadIdx.x;
  const int wave = tid >> 6, lane = tid & 63;
  const int quad = lane >> 4, col = lane & 15;
  const int tile_m = blockIdx.y * 128, tile_n = blockIdx.x * 128;
  const int mb = (wave >> 1) * 64, nb = (wave & 1) * 64;
  // staging: chunk c = 2*wave + i covers rows c*16..c*16+15, lane -> (row = lane>>2, colchunk = lane&3)
  const int srow = lane >> 2, scol = (lane & 3) * 8;
  const f16* gA = A + (size_t)(tile_m + wave * 32 + srow) * K + scol;
  const f16* gB = B + (size_t)(tile_n + wave * 32 + srow) * K + scol;
  f16* lA = As + wave * 1024;
  f16* lB = Bs + wave * 1024;

  f32x4 acc[4][4] = {};
  for (int k0 = 0; k0 < K; k0 += 32) {
    gl2lds16(gA + k0,          lA);
    gl2lds16(gA + 16 * K + k0, lA + 512);
    gl2lds16(gB + k0,          lB);
    gl2lds16(gB + 16 * K + k0, lB + 512);
    __syncthreads();
    f16x8 af[4], bf[4];
    #pragma unroll
    for (int i = 0; i < 4; ++i)
      af[i] = *(const f16x8*)&As[(mb + i * 16 + col) * 32 + quad * 8];
    #pragma unroll
    for (int j = 0; j < 4; ++j)
      bf[j] = *(const f16x8*)&Bs[(nb + j * 16 + col) * 32 + quad * 8];
    #pragma unroll
    for (int i = 0; i < 4; ++i)
      #pragma unroll
      for (int j = 0; j < 4; ++j)
        acc[i][j] = mfma16(af[i], bf[j], acc[i][j]);
    __syncthreads();
  }

  #pragma unroll
  for (int j = 0; j < 4; ++j) {
    const int gn = tile_n + nb + j * 16 + col;
    if (MODE == 0) {
      const int which = gn >> 10;
      const int d = gn & 1023;
      const float* bp = (which == 0) ? bias0 : (which == 1) ? bias1 : bias2;
      f16* dst        = (which == 0) ? Qp    : (which == 1) ? Kp    : Vp;
      const float bvv = bp[d];
      const int h = d >> 6, hi = d & 63;
      #pragma unroll
      for (int i = 0; i < 4; ++i) {
        #pragma unroll
        for (int r = 0; r < 4; ++r) {
          const int gm = tile_m + mb + i * 16 + quad * 4 + r;
          const int bb = gm >> 11, s = gm & 2047;
          dst[(((size_t)bb * 16 + h) * 2048 + s) * 64 + hi] = (f16)(acc[i][j][r] + bvv);
        }
      }
    } else {
      const float bvv = bias0[gn];
      #pragma unroll
      for (int i = 0; i < 4; ++i) {
        #pragma unroll
        for (int r = 0; r < 4; ++r) {
          const int gm = tile_m + mb + i * 16 + quad * 4 + r;
          OutF[(size_t)gm * 1024 + gn] = acc[i][j][r] + bvv;
        }
      }
    }
  }
}

// ---------------- flash attention: 64-row Q tile per block, 4 waves x 16 rows ----------------
__global__ __launch_bounds__(256) void attn_kernel(
    const f16* __restrict__ Q, const f16* __restrict__ Kt, const f16* __restrict__ V,
    f16* __restrict__ ctx)
{
  __shared__ __align__(16) f16 Ks[64][80];    // [kv][d], pad 80: 2-way only
  __shared__ __align__(16) f16 Vts[64][80];   // [d][kv] (transposed at staging)
  __shared__ __align__(16) f16 Ps[4][16][80]; // per-wave P round-trip
  const int bh = blockIdx.y;         // b*16 + h
  const int qt = blockIdx.x;
  const int q0 = qt * 64;
  const int tid  = threadIdx.x;
  const int wave = tid >> 6, lane = tid & 63;
  const int quad = lane >> 4, col = lane & 15;
  const size_t base = (size_t)bh * 2048 * 64;

  // Q fragments in registers (A-layout: row=lane&15, k=quad*8+j), loop-invariant
  const int qrow = q0 + wave * 16 + col;
  const f16x8 aq0 = *(const f16x8*)&Q[base + (size_t)qrow * 64 + quad * 8];
  const f16x8 aq1 = *(const f16x8*)&Q[base + (size_t)qrow * 64 + 32 + quad * 8];

  f32x4 ctxa[4] = {};
  float m_r[4] = {-INFINITY, -INFINITY, -INFINITY, -INFINITY};
  float l_r[4] = {0.f, 0.f, 0.f, 0.f};

  for (int t = 0; t <= qt; ++t) {
    __syncthreads();   // prior iteration's LDS reads complete
    #pragma unroll
    for (int i = 0; i < 2; ++i) {
      const int flat = tid + i * 256;
      // K: coalesced rows
      const int krow = flat >> 3, kcol = (flat & 7) * 8;
      *(f16x8*)&Ks[krow][kcol] = *(const f16x8*)&Kt[base + (size_t)(t * 64 + krow) * 64 + kcol];
      // V: transpose-store; lane->row mapping makes ds_write_b16 conflict-free
      const int vrow = flat & 63, vcc = flat >> 6;
      const f16x8 vv = *(const f16x8*)&V[base + (size_t)(t * 64 + vrow) * 64 + vcc * 8];
      #pragma unroll
      for (int jj = 0; jj < 8; ++jj) Vts[vcc * 8 + jj][vrow] = vv[jj];
    }
    __syncthreads();

    // S = Q K^T (scaled)
    f32x4 s[4] = {};
    #pragma unroll
    for (int jt = 0; jt < 4; ++jt) {
      const f16x8 bk0 = *(const f16x8*)&Ks[jt * 16 + col][quad * 8];
      const f16x8 bk1 = *(const f16x8*)&Ks[jt * 16 + col][32 + quad * 8];
      s[jt] = mfma16(aq0, bk0, s[jt]);
      s[jt] = mfma16(aq1, bk1, s[jt]);
    }
    const bool diag = (t == qt);
    #pragma unroll
    for (int jt = 0; jt < 4; ++jt) {
      #pragma unroll
      for (int r = 0; r < 4; ++r) {
        float v = s[jt][r] * 0.125f;   // 1/sqrt(64)
        if (diag) {
          const int kg = t * 64 + jt * 16 + col;
          const int qg = q0 + wave * 16 + quad * 4 + r;
          if (kg > qg) v = -1e30f;
        }
        s[jt][r] = v;
      }
    }
    // online softmax, per C-layout row r (row stats shuffle-reduced across the 16-lane col group)
    #pragma unroll
    for (int r = 0; r < 4; ++r) {
      float tm = fmaxf(fmaxf(s[0][r], s[1][r]), fmaxf(s[2][r], s[3][r]));
      #pragma unroll
      for (int off = 1; off < 16; off <<= 1) tm = fmaxf(tm, __shfl_xor(tm, off));
      const float mnew  = fmaxf(m_r[r], tm);
      const float alpha = __expf(m_r[r] - mnew);   // first tile: exp(-inf)=0
      float rs = 0.f;
      #pragma unroll
      for (int jt = 0; jt < 4; ++jt) {
        const float p = __expf(s[jt][r] - mnew);
        s[jt][r] = p;
        rs += p;
      }
      #pragma unroll
      for (int off = 1; off < 16; off <<= 1) rs += __shfl_xor(rs, off);
      m_r[r] = mnew;
      l_r[r] = l_r[r] * alpha + rs;
      #pragma unroll
      for (int jt = 0; jt < 4; ++jt) ctxa[jt][r] *= alpha;
    }
    // P: C-layout -> row-major LDS (own wave slab; same-wave RAW, lgkmcnt drain suffices)
    #pragma unroll
    for (int jt = 0; jt < 4; ++jt)
      #pragma unroll
      for (int r = 0; r < 4; ++r)
        Ps[wave][quad * 4 + r][jt * 16 + col] = (f16)s[jt][r];
    __asm__ volatile("s_waitcnt lgkmcnt(0)" ::: "memory");

    // ctx += P V  (NT with Vts = V^T)
    const f16x8 ap0 = *(const f16x8*)&Ps[wave][col][quad * 8];
    const f16x8 ap1 = *(const f16x8*)&Ps[wave][col][32 + quad * 8];
    #pragma unroll
    for (int jt = 0; jt < 4; ++jt) {
      const f16x8 bv0 = *(const f16x8*)&Vts[jt * 16 + col][quad * 8];
      const f16x8 bv1 = *(const f16x8*)&Vts[jt * 16 + col][32 + quad * 8];
      ctxa[jt] = mfma16(ap0, bv0, ctxa[jt]);
      ctxa[jt] = mfma16(ap1, bv1, ctxa[jt]);
    }
  }

  // epilogue: ctx/l -> [B,S,D] f16 for the O projection
  const int b = bh >> 4, h = bh & 15;
  #pragma unroll
  for (int jt = 0; jt < 4; ++jt) {
    #pragma unroll
    for (int r = 0; r < 4; ++r) {
      const int q = q0 + wave * 16 + quad * 4 + r;
      const int d = h * 64 + jt * 16 + col;
      ctx[((size_t)b * 2048 + q) * 1024 + d] = (f16)(ctxa[jt][r] / l_r[r]);
    }
  }
}

extern "C" void kernel_launch(void* const* d_in, const int* in_sizes, int n_in,
                              void* d_out, int out_size, void* d_ws, size_t ws_size,
                              hipStream_t stream)
{
  const float* x  = (const float*)d_in[0];
  const float* Wq = (const float*)d_in[1];
  const float* bq = (const float*)d_in[2];
  const float* Wk = (const float*)d_in[3];
  const float* bk = (const float*)d_in[4];
  const float* Wv = (const float*)d_in[5];
  const float* bv = (const float*)d_in[6];
  const float* Wo = (const float*)d_in[7];
  const float* bo = (const float*)d_in[8];
  float* out = (float*)d_out;

  f16* ws = (f16*)d_ws;
  const size_t M1 = 1048576;
  f16* xh    = ws;             // 4M halves
  f16* wqkvh = ws + 4  * M1;   // 3M
  f16* woh   = ws + 7  * M1;   // 1M
  f16* Qh    = ws + 8  * M1;   // 4M  [B,H,S,64]
  f16* Kh    = ws + 12 * M1;   // 4M  [B,H,S,64]
  f16* Vh    = ws + 16 * M1;   // 4M  [B,H,S,64]
  f16* ctxh  = ws + 20 * M1;   // 4M  [B,S,D]     (total 48 MB)

  cvt_kernel<<<dim3(2048, 5), 256, 0, stream>>>(x, Wq, Wk, Wv, Wo, xh, wqkvh, woh);
  gemm_nt<0><<<dim3(24, 32), 256, 0, stream>>>(xh, wqkvh, bq, bk, bv, Qh, Kh, Vh, nullptr);
  attn_kernel<<<dim3(32, 32), 256, 0, stream>>>(Qh, Kh, Vh, ctxh);
  gemm_nt<1><<<dim3(8, 32), 256, 0, stream>>>(ctxh, woh, bo, nullptr, nullptr, nullptr,
                                              nullptr, nullptr, out);
}

// Round 2
// 206.527 us; speedup vs baseline: 1.3043x; 1.3043x over previous
//
#include <hip/hip_runtime.h>
#include <cstdint>
#include <math.h>

typedef _Float16 f16;
typedef _Float16 f16x8 __attribute__((ext_vector_type(8)));
typedef float    f32x4 __attribute__((ext_vector_type(4)));

__device__ __forceinline__ f32x4 mfma16(f16x8 a, f16x8 b, f32x4 c) {
  return __builtin_amdgcn_mfma_f32_16x16x32_f16(a, b, c, 0, 0, 0);
}

// async global->LDS, 16B per lane; deposit = wave-uniform base + lane*16
__device__ __forceinline__ void gl2lds16(const f16* g, f16* l) {
  __builtin_amdgcn_global_load_lds((__attribute__((address_space(1))) void*)(g),
                                   (__attribute__((address_space(3))) void*)(l),
                                   16, 0, 0);
}

// DPP rotate within 16-lane rows (quad groups == DPP rows on wave64)
template<int CTRL>
__device__ __forceinline__ float dpp_ror(float x) {
  return __int_as_float(__builtin_amdgcn_update_dpp(
      0, __float_as_int(x), CTRL, 0xF, 0xF, true));
}
__device__ __forceinline__ float rmax16(float v) {
  v = fmaxf(v, dpp_ror<0x121>(v));   // row_ror:1
  v = fmaxf(v, dpp_ror<0x122>(v));   // row_ror:2
  v = fmaxf(v, dpp_ror<0x124>(v));   // row_ror:4
  v = fmaxf(v, dpp_ror<0x128>(v));   // row_ror:8
  return v;
}
__device__ __forceinline__ float rsum16(float v) {
  v += dpp_ror<0x121>(v);
  v += dpp_ror<0x122>(v);
  v += dpp_ror<0x124>(v);
  v += dpp_ror<0x128>(v);
  return v;
}
__device__ __forceinline__ float fexp2(float x) { return __builtin_amdgcn_exp2f(x); }

// ---------------- fp32 -> f16 conversion of x, Wq|Wk|Wv (stacked), Wo ----------------
__global__ __launch_bounds__(256) void cvt_kernel(
    const float* __restrict__ x,  const float* __restrict__ wq, const float* __restrict__ wk,
    const float* __restrict__ wv, const float* __restrict__ wo,
    f16* __restrict__ xh, f16* __restrict__ wqkvh, f16* __restrict__ woh)
{
  const int seg = blockIdx.y;
  const float* src; f16* dst; int n;
  if      (seg == 0) { src = x;  dst = xh;              n = 4194304; }
  else if (seg == 1) { src = wq; dst = wqkvh;           n = 1048576; }
  else if (seg == 2) { src = wk; dst = wqkvh + 1048576; n = 1048576; }
  else if (seg == 3) { src = wv; dst = wqkvh + 2097152; n = 1048576; }
  else               { src = wo; dst = woh;             n = 1048576; }
  const int idx = (int)(blockIdx.x * 256 + threadIdx.x) * 8;
  if (idx >= n) return;
  f32x4 a = *(const f32x4*)(src + idx);
  f32x4 b = *(const f32x4*)(src + idx + 4);
  f16x8 h;
  h[0] = (f16)a[0]; h[1] = (f16)a[1]; h[2] = (f16)a[2]; h[3] = (f16)a[3];
  h[4] = (f16)b[0]; h[5] = (f16)b[1]; h[6] = (f16)b[2]; h[7] = (f16)b[3];
  *(f16x8*)(dst + idx) = h;
}

// ---------------- NT GEMM, 128x128 tile, BK=32, m97-style staging ----------------
template<int MODE>
__global__ __launch_bounds__(256) void gemm_nt(
    const f16* __restrict__ A, const f16* __restrict__ B,
    const float* __restrict__ bias0, const float* __restrict__ bias1, const float* __restrict__ bias2,
    f16* __restrict__ Qp, f16* __restrict__ Kp, f16* __restrict__ Vp,
    float* __restrict__ OutF)
{
  constexpr int K = 1024;
  __shared__ __align__(16) f16 As[128 * 32];
  __shared__ __align__(16) f16 Bs[128 * 32];
  const int tid  = threadIdx.x;
  const int wave = tid >> 6, lane = tid & 63;
  const int quad = lane >> 4, col = lane & 15;
  const int tile_m = blockIdx.y * 128, tile_n = blockIdx.x * 128;
  const int mb = (wave >> 1) * 64, nb = (wave & 1) * 64;
  const int srow = lane >> 2, scol = (lane & 3) * 8;
  const f16* gA = A + (size_t)(tile_m + wave * 32 + srow) * K + scol;
  const f16* gB = B + (size_t)(tile_n + wave * 32 + srow) * K + scol;
  f16* lA = As + wave * 1024;
  f16* lB = Bs + wave * 1024;

  f32x4 acc[4][4] = {};
  for (int k0 = 0; k0 < K; k0 += 32) {
    gl2lds16(gA + k0,          lA);
    gl2lds16(gA + 16 * K + k0, lA + 512);
    gl2lds16(gB + k0,          lB);
    gl2lds16(gB + 16 * K + k0, lB + 512);
    __syncthreads();
    f16x8 af[4], bf[4];
    #pragma unroll
    for (int i = 0; i < 4; ++i)
      af[i] = *(const f16x8*)&As[(mb + i * 16 + col) * 32 + quad * 8];
    #pragma unroll
    for (int j = 0; j < 4; ++j)
      bf[j] = *(const f16x8*)&Bs[(nb + j * 16 + col) * 32 + quad * 8];
    #pragma unroll
    for (int i = 0; i < 4; ++i)
      #pragma unroll
      for (int j = 0; j < 4; ++j)
        acc[i][j] = mfma16(af[i], bf[j], acc[i][j]);
    __syncthreads();
  }

  #pragma unroll
  for (int j = 0; j < 4; ++j) {
    const int gn = tile_n + nb + j * 16 + col;
    if (MODE == 0) {
      const int which = gn >> 10;
      const int d = gn & 1023;
      const float* bp = (which == 0) ? bias0 : (which == 1) ? bias1 : bias2;
      f16* dst        = (which == 0) ? Qp    : (which == 1) ? Kp    : Vp;
      const float bvv = bp[d];
      const int h = d >> 6, hi = d & 63;
      #pragma unroll
      for (int i = 0; i < 4; ++i) {
        #pragma unroll
        for (int r = 0; r < 4; ++r) {
          const int gm = tile_m + mb + i * 16 + quad * 4 + r;
          const int bb = gm >> 11, s = gm & 2047;
          dst[(((size_t)bb * 16 + h) * 2048 + s) * 64 + hi] = (f16)(acc[i][j][r] + bvv);
        }
      }
    } else {
      const float bvv = bias0[gn];
      #pragma unroll
      for (int i = 0; i < 4; ++i) {
        #pragma unroll
        for (int r = 0; r < 4; ++r) {
          const int gm = tile_m + mb + i * 16 + quad * 4 + r;
          OutF[(size_t)gm * 1024 + gn] = acc[i][j][r] + bvv;
        }
      }
    }
  }
}

// ---------------- flash attention ----------------
// Block: 4 waves x 16 Q rows = 64-row Q tile; paired tiles (bx, 31-bx) for load balance.
// DPP softmax reductions; register prefetch of next K/V tile; exp2-domain softmax.
__global__ __launch_bounds__(256) void attn_kernel(
    const f16* __restrict__ Q, const f16* __restrict__ Kt, const f16* __restrict__ V,
    f16* __restrict__ ctx)
{
  __shared__ __align__(16) f16 Ks[64][80];    // [kv][d]
  __shared__ __align__(16) f16 Vts[64][80];   // [d][kv] (transposed at staging)
  __shared__ __align__(16) f16 Ps[4][16][80]; // per-wave P round-trip
  const int bh = blockIdx.y;                  // b*16 + h
  const int tid  = threadIdx.x;
  const int wave = tid >> 6, lane = tid & 63;
  const int quad = lane >> 4, col = lane & 15;
  const size_t base = (size_t)bh * 2048 * 64;
  const int b = bh >> 4, h = bh & 15;
  const float scale2 = 0.125f * 1.44269504f;  // 1/sqrt(64) * log2(e)

  auto run_tile = [&](int qt) {
    const int q0 = qt * 64;
    const int qrow = q0 + wave * 16 + col;
    const f16x8 aq0 = *(const f16x8*)&Q[base + (size_t)qrow * 64 + quad * 8];
    const f16x8 aq1 = *(const f16x8*)&Q[base + (size_t)qrow * 64 + 32 + quad * 8];

    f32x4 ctxa[4] = {};
    float m_r[4] = {-INFINITY, -INFINITY, -INFINITY, -INFINITY};
    float l_r[4] = {0.f, 0.f, 0.f, 0.f};

    f16x8 kr[2], vr[2];
    auto gload = [&](int t) {
      #pragma unroll
      for (int i = 0; i < 2; ++i) {
        const int flat = tid + i * 256;
        const int krow = flat >> 3, kcol = (flat & 7) * 8;
        kr[i] = *(const f16x8*)&Kt[base + (size_t)(t * 64 + krow) * 64 + kcol];
        const int vrow = flat & 63, vcc = flat >> 6;
        vr[i] = *(const f16x8*)&V[base + (size_t)(t * 64 + vrow) * 64 + vcc * 8];
      }
    };
    gload(0);

    for (int t = 0; t <= qt; ++t) {
      __syncthreads();   // prior iteration's LDS reads complete
      #pragma unroll
      for (int i = 0; i < 2; ++i) {
        const int flat = tid + i * 256;
        const int krow = flat >> 3, kcol = (flat & 7) * 8;
        *(f16x8*)&Ks[krow][kcol] = kr[i];
        const int vrow = flat & 63, vcc = flat >> 6;
        #pragma unroll
        for (int jj = 0; jj < 8; ++jj) Vts[vcc * 8 + jj][vrow] = vr[i][jj];
      }
      __syncthreads();
      if (t < qt) gload(t + 1);   // prefetch: in flight during compute

      // S = Q K^T
      f32x4 s[4] = {};
      #pragma unroll
      for (int jt = 0; jt < 4; ++jt) {
        const f16x8 bk0 = *(const f16x8*)&Ks[jt * 16 + col][quad * 8];
        const f16x8 bk1 = *(const f16x8*)&Ks[jt * 16 + col][32 + quad * 8];
        s[jt] = mfma16(aq0, bk0, s[jt]);
        s[jt] = mfma16(aq1, bk1, s[jt]);
      }
      if (t == qt) {  // diagonal tile: causal mask
        #pragma unroll
        for (int jt = 0; jt < 4; ++jt) {
          const int kg = t * 64 + jt * 16 + col;
          #pragma unroll
          for (int r = 0; r < 4; ++r) {
            const int qg = q0 + wave * 16 + quad * 4 + r;
            s[jt][r] = (kg > qg) ? -1e30f : s[jt][r] * scale2;
          }
        }
      } else {
        #pragma unroll
        for (int jt = 0; jt < 4; ++jt)
          #pragma unroll
          for (int r = 0; r < 4; ++r) s[jt][r] *= scale2;
      }

      // online softmax (exp2 domain), DPP reductions over the 16-lane row
      #pragma unroll
      for (int r = 0; r < 4; ++r) {
        float tm = fmaxf(fmaxf(s[0][r], s[1][r]), fmaxf(s[2][r], s[3][r]));
        tm = rmax16(tm);
        const float mnew  = fmaxf(m_r[r], tm);
        const float alpha = fexp2(m_r[r] - mnew);   // first tile: 2^(-inf)=0
        float rs = 0.f;
        #pragma unroll
        for (int jt = 0; jt < 4; ++jt) {
          const float p = fexp2(s[jt][r] - mnew);
          s[jt][r] = p;
          rs += p;
        }
        rs = rsum16(rs);
        m_r[r] = mnew;
        l_r[r] = l_r[r] * alpha + rs;
        #pragma unroll
        for (int jt = 0; jt < 4; ++jt) ctxa[jt][r] *= alpha;
      }

      // P: C-layout -> row-major LDS (own wave slab; same-wave RAW -> lgkmcnt drain)
      #pragma unroll
      for (int jt = 0; jt < 4; ++jt)
        #pragma unroll
        for (int r = 0; r < 4; ++r)
          Ps[wave][quad * 4 + r][jt * 16 + col] = (f16)s[jt][r];
      __asm__ volatile("s_waitcnt lgkmcnt(0)" ::: "memory");

      // ctx += P V
      const f16x8 ap0 = *(const f16x8*)&Ps[wave][col][quad * 8];
      const f16x8 ap1 = *(const f16x8*)&Ps[wave][col][32 + quad * 8];
      #pragma unroll
      for (int jt = 0; jt < 4; ++jt) {
        const f16x8 bv0 = *(const f16x8*)&Vts[jt * 16 + col][quad * 8];
        const f16x8 bv1 = *(const f16x8*)&Vts[jt * 16 + col][32 + quad * 8];
        ctxa[jt] = mfma16(ap0, bv0, ctxa[jt]);
        ctxa[jt] = mfma16(ap1, bv1, ctxa[jt]);
      }
    }

    // epilogue -> [B,S,D] f16 for the O projection
    #pragma unroll
    for (int jt = 0; jt < 4; ++jt) {
      #pragma unroll
      for (int r = 0; r < 4; ++r) {
        const int q = q0 + wave * 16 + quad * 4 + r;
        const int d = h * 64 + jt * 16 + col;
        ctx[((size_t)b * 2048 + q) * 1024 + d] = (f16)(ctxa[jt][r] / l_r[r]);
      }
    }
  };

  run_tile(blockIdx.x);        // tiles 0..15
  run_tile(31 - blockIdx.x);   // tiles 31..16  -> every block does 33 K-tile iters
}

extern "C" void kernel_launch(void* const* d_in, const int* in_sizes, int n_in,
                              void* d_out, int out_size, void* d_ws, size_t ws_size,
                              hipStream_t stream)
{
  const float* x  = (const float*)d_in[0];
  const float* Wq = (const float*)d_in[1];
  const float* bq = (const float*)d_in[2];
  const float* Wk = (const float*)d_in[3];
  const float* bk = (const float*)d_in[4];
  const float* Wv = (const float*)d_in[5];
  const float* bv = (const float*)d_in[6];
  const float* Wo = (const float*)d_in[7];
  const float* bo = (const float*)d_in[8];
  float* out = (float*)d_out;

  f16* ws = (f16*)d_ws;
  const size_t M1 = 1048576;
  f16* xh    = ws;             // 4M halves
  f16* wqkvh = ws + 4  * M1;   // 3M
  f16* woh   = ws + 7  * M1;   // 1M
  f16* Qh    = ws + 8  * M1;   // 4M  [B,H,S,64]
  f16* Kh    = ws + 12 * M1;   // 4M  [B,H,S,64]
  f16* Vh    = ws + 16 * M1;   // 4M  [B,H,S,64]
  f16* ctxh  = ws + 20 * M1;   // 4M  [B,S,D]

  cvt_kernel<<<dim3(2048, 5), 256, 0, stream>>>(x, Wq, Wk, Wv, Wo, xh, wqkvh, woh);
  gemm_nt<0><<<dim3(24, 32), 256, 0, stream>>>(xh, wqkvh, bq, bk, bv, Qh, Kh, Vh, nullptr);
  attn_kernel<<<dim3(16, 32), 256, 0, stream>>>(Qh, Kh, Vh, ctxh);
  gemm_nt<1><<<dim3(8, 32), 256, 0, stream>>>(ctxh, woh, bo, nullptr, nullptr, nullptr,
                                              nullptr, nullptr, out);
}